// Round 8
// baseline (121.574 us; speedup 1.0000x reference)
//
#include <hip/hip_runtime.h>

typedef short short8  __attribute__((ext_vector_type(8)));
typedef short short4v __attribute__((ext_vector_type(4)));
typedef float f32x4   __attribute__((ext_vector_type(4)));

#define NSPLIT 16

static __device__ __forceinline__ unsigned short f2bf(float f) {
  unsigned int u = __builtin_bit_cast(unsigned int, f);
  u += 0x7fffu + ((u >> 16) & 1u);   // RNE
  return (unsigned short)(u >> 16);
}
// pack two f32 -> two bf16 (RTZ) in ONE v_perm_b32: D = [hi.b3 hi.b2 lo.b3 lo.b2]
static __device__ __forceinline__ unsigned int pack2bf_rtz(float lo, float hi) {
  return __builtin_amdgcn_perm(__builtin_bit_cast(unsigned int, hi),
                               __builtin_bit_cast(unsigned int, lo), 0x07060302u);
}

// ---------------------------------------------------------------------------
// Kernel 1: QKV projection GEMM, rt-split (grid 6x64x4, 24 waves/CU).
// rt0=Q (PRE-SCALED by log2(e) so flash can use exp2), rt1=K, rt2..5=V rows.
// Q,K -> bf16 [b][n][16]; V -> bf16 [b][c][n].
// ---------------------------------------------------------------------------
__global__ __launch_bounds__(256) void qkv_mfma(
    const float* __restrict__ x,
    const float* __restrict__ Wq, const float* __restrict__ bq,
    const float* __restrict__ Wk, const float* __restrict__ bk,
    const float* __restrict__ Wv, const float* __restrict__ bv,
    unsigned short* __restrict__ qb, unsigned short* __restrict__ kb,
    unsigned short* __restrict__ vb)
{
  const int rt   = blockIdx.x;         // 0..5
  const int nt   = blockIdx.y;         // 0..63
  const int b    = blockIdx.z;         // 0..3
  const int lane = threadIdx.x & 63;
  const int wave = threadIdx.x >> 6;
  const int l15  = lane & 15;
  const int quad = lane >> 4;
  const int n    = nt * 64 + wave * 16 + l15;

  const float* wbase; const float* bias; int row0;
  if (rt == 0)      { wbase = Wq; bias = bq; row0 = 0; }
  else if (rt == 1) { wbase = Wk; bias = bk; row0 = 0; }
  else              { wbase = Wv; bias = bv; row0 = (rt - 2) * 16; }

  short8 bfrag[2];
#pragma unroll
  for (int ks = 0; ks < 2; ++ks)
#pragma unroll
    for (int jj = 0; jj < 8; ++jj) {
      const int c = ks * 32 + quad * 8 + jj;
      bfrag[ks][jj] = (short)f2bf(x[((size_t)(b * 64 + c)) * 4096 + n]);
    }

  short8 afrag[2];
#pragma unroll
  for (int ks = 0; ks < 2; ++ks) {
    f32x4 w0 = *(const f32x4*)(wbase + (row0 + l15) * 64 + ks * 32 + quad * 8);
    f32x4 w1 = *(const f32x4*)(wbase + (row0 + l15) * 64 + ks * 32 + quad * 8 + 4);
#pragma unroll
    for (int jj = 0; jj < 4; ++jj) {
      afrag[ks][jj]     = (short)f2bf(w0[jj]);
      afrag[ks][jj + 4] = (short)f2bf(w1[jj]);
    }
  }

  f32x4 acc;
#pragma unroll
  for (int r = 0; r < 4; ++r)
    acc[r] = bias[row0 + quad * 4 + r];
  acc = __builtin_amdgcn_mfma_f32_16x16x32_bf16(afrag[0], bfrag[0], acc, 0, 0, 0);
  acc = __builtin_amdgcn_mfma_f32_16x16x32_bf16(afrag[1], bfrag[1], acc, 0, 0, 0);

  if (rt <= 1) {
    if (rt == 0) {
#pragma unroll
      for (int r = 0; r < 4; ++r) acc[r] *= 1.44269504088896340736f;  // log2(e)
    }
    short4v sv;
#pragma unroll
    for (int r = 0; r < 4; ++r) sv[r] = (short)f2bf(acc[r]);
    unsigned short* dst = (rt == 0 ? qb : kb);
    *(short4v*)(dst + (((size_t)b * 4096 + n) * 16) + quad * 4) = sv;
  } else {
#pragma unroll
    for (int r = 0; r < 4; ++r) {
      const int c = row0 + quad * 4 + r;
      vb[((size_t)(b * 64 + c)) * 4096 + n] = f2bf(acc[r]);
    }
  }
}

// ---------------------------------------------------------------------------
// Kernel 2: flash partials, 64 queries per wave, SOFTWARE-PIPELINED j-loop:
//   - vf (8 b128) issued at iter top -> in flight under the S/exp/pack phase
//   - kf for iter j+1 issued before the PV phase -> in flight under PV
//   - only iter 0 pays exposed K latency
// Barrier-free; P via per-wave swizzled LDS; exp2 (Q pre-scaled by log2 e).
// ---------------------------------------------------------------------------
__global__ __launch_bounds__(256) void flash_attn(
    const unsigned short* __restrict__ qb, const unsigned short* __restrict__ kb,
    const unsigned short* __restrict__ vb,
    float* __restrict__ Opart, float* __restrict__ lpart)
{
  __shared__ unsigned short p_lds[4][64 * 64];   // per-wave [q64][j64], swizzled

  const int s    = blockIdx.x;          // 0..NSPLIT-1
  const int qw4  = blockIdx.y;          // 0..15
  const int b    = blockIdx.z;          // 0..3
  const int t    = threadIdx.x;
  const int wave = t >> 6;
  const int lane = t & 63;
  const int l15  = lane & 15;
  const int quad = lane >> 4;
  const int sw   = l15 & 7;
  const int qw   = qw4 * 4 + wave;      // 64-query wave index 0..63

  short8 qfrag[4];
#pragma unroll
  for (int qt = 0; qt < 4; ++qt) {
    qfrag[qt] = (short8)0;
    if (quad < 2) {
      const int iq = qw * 64 + qt * 16 + l15;
      qfrag[qt] = *(const short8*)(qb + (((size_t)b * 4096 + iq) * 16 + quad * 8));
    }
  }

  const unsigned short* vbb = vb + (size_t)b * 64 * 4096;
  const unsigned short* kbb = kb + (size_t)b * 4096 * 16;
  f32x4 acc[4][4];
#pragma unroll
  for (int qt = 0; qt < 4; ++qt)
#pragma unroll
    for (int ct = 0; ct < 4; ++ct) acc[qt][ct] = (f32x4)0.f;
  float lp[4] = {0.f, 0.f, 0.f, 0.f};
  unsigned short* pw = &p_lds[wave][0];

  const int jbeg = s * (4096 / NSPLIT);
  const int jend = jbeg + 4096 / NSPLIT;

  // ---- prologue: K fragments for the first iteration ----
  short8 kf[4];
#pragma unroll
  for (int sub = 0; sub < 4; ++sub) {
    kf[sub] = (short8)0;
    if (quad < 2)
      kf[sub] = *(const short8*)(kbb + (size_t)(jbeg + sub * 16 + l15) * 16 + quad * 8);
  }

#pragma unroll 1
  for (int j0 = jbeg; j0 < jend; j0 += 64) {
    // ---- issue all V loads for this iter (no dependence on S/P phase) ----
    short8 vf[2][4];
#pragma unroll
    for (int kc = 0; kc < 2; ++kc) {
      const int vcol = j0 + kc * 32 + quad * 8;
#pragma unroll
      for (int ct = 0; ct < 4; ++ct)
        vf[kc][ct] = *(const short8*)(vbb + (size_t)(ct * 16 + l15) * 4096 + vcol);
    }

    // ---- S^T = K Q^T, P = exp2 -> per-wave LDS (RTZ bf16 pack) ----
#pragma unroll
    for (int qt = 0; qt < 4; ++qt) {
#pragma unroll
      for (int sub = 0; sub < 4; ++sub) {
        f32x4 sc = __builtin_amdgcn_mfma_f32_16x16x32_bf16(kf[sub], qfrag[qt], (f32x4)0.f, 0, 0, 0);
        float p0 = exp2f(sc[0]);
        float p1 = exp2f(sc[1]);
        float p2 = exp2f(sc[2]);
        float p3 = exp2f(sc[3]);
        lp[qt] += (p0 + p1) + (p2 + p3);
        const int ch = (sub * 2 + (quad >> 1)) ^ sw;
        unsigned int* dst = (unsigned int*)(pw + (qt * 16 + l15) * 64 + ch * 8 + (quad & 1) * 4);
        dst[0] = pack2bf_rtz(p0, p1);
        dst[1] = pack2bf_rtz(p2, p3);
      }
    }

    // ---- prefetch K for the NEXT iter; latency hidden under PV ----
    short8 kfn[4];
    const int jn = j0 + 64;
    const bool more = (jn < jend);
#pragma unroll
    for (int sub = 0; sub < 4; ++sub) {
      kfn[sub] = (short8)0;
      if (more && quad < 2)
        kfn[sub] = *(const short8*)(kbb + (size_t)(jn + sub * 16 + l15) * 16 + quad * 8);
    }

    // ---- O += V P ----
#pragma unroll
    for (int kc = 0; kc < 2; ++kc) {
#pragma unroll
      for (int qt = 0; qt < 4; ++qt) {
        short8 pf = *(const short8*)(pw + (qt * 16 + l15) * 64 + ((kc * 4 + quad) ^ sw) * 8);
#pragma unroll
        for (int ct = 0; ct < 4; ++ct)
          acc[qt][ct] = __builtin_amdgcn_mfma_f32_16x16x32_bf16(vf[kc][ct], pf, acc[qt][ct], 0, 0, 0);
      }
    }

#pragma unroll
    for (int sub = 0; sub < 4; ++sub) kf[sub] = kfn[sub];
  }

#pragma unroll
  for (int qt = 0; qt < 4; ++qt) {
    lp[qt] += __shfl_xor(lp[qt], 16);
    lp[qt] += __shfl_xor(lp[qt], 32);
  }

  const int pslot = (b * 64 + qw) * NSPLIT + s;
  float* Op = Opart + (size_t)pslot * 4096;       // [q64][c64]
#pragma unroll
  for (int qt = 0; qt < 4; ++qt)
#pragma unroll
    for (int ct = 0; ct < 4; ++ct)
      *(f32x4*)(Op + (qt * 16 + l15) * 64 + ct * 16 + quad * 4) = acc[qt][ct];
  if (lane < 16) {
#pragma unroll
    for (int qt = 0; qt < 4; ++qt)
      lpart[(size_t)pslot * 64 + qt * 16 + lane] = lp[qt];
  }
}

// ---------------------------------------------------------------------------
// Kernel 3: combine splits, normalize, gamma*O + x.  Grid 64x4, 1024 thr.
// ---------------------------------------------------------------------------
__global__ __launch_bounds__(1024) void finalize(
    const float* __restrict__ Opart, const float* __restrict__ lpart,
    const float* __restrict__ x, const float* __restrict__ gptr,
    float* __restrict__ out)
{
  __shared__ float osum[64 * 65];
  __shared__ float linv[64];

  const int qw = blockIdx.x;            // 0..63 (64-query group)
  const int b  = blockIdx.y;            // 0..3
  const int t  = threadIdx.x;           // 0..1023
  const int base = (b * 64 + qw) * NSPLIT;

  if (t < 64) {
    float sum = 0.f;
#pragma unroll
    for (int s = 0; s < NSPLIT; ++s) sum += lpart[(size_t)(base + s) * 64 + t];
    linv[t] = 1.f / sum;
  }

  f32x4 o = (f32x4)0.f;
  const float* Op = Opart + (size_t)base * 4096;
#pragma unroll
  for (int s = 0; s < NSPLIT; ++s)
    o += *(const f32x4*)(Op + (size_t)s * 4096 + 4 * t);

  // element (q = t>>4, c = (t&15)*4 + r)  ->  osum[c][q]
  const int q  = t >> 4;
  const int c0 = (t & 15) * 4;
#pragma unroll
  for (int r = 0; r < 4; ++r)
    osum[(c0 + r) * 65 + q] = o[r];
  __syncthreads();

  const float g  = gptr[0];
  const int   qq = t & 63;
  const float li = linv[qq];
#pragma unroll
  for (int i = 0; i < 4; ++i) {
    const int c = (t >> 6) + 16 * i;
    const size_t off = ((size_t)(b * 64 + c)) * 4096 + qw * 64 + qq;
    out[off] = g * (osum[c * 65 + qq] * li) + x[off];
  }
}

// ---------------------------------------------------------------------------
extern "C" void kernel_launch(void* const* d_in, const int* in_sizes, int n_in,
                              void* d_out, int out_size, void* d_ws, size_t ws_size,
                              hipStream_t stream)
{
  const float* x  = (const float*)d_in[0];
  const float* Wq = (const float*)d_in[1];
  const float* bq = (const float*)d_in[2];
  const float* Wk = (const float*)d_in[3];
  const float* bk = (const float*)d_in[4];
  const float* Wv = (const float*)d_in[5];
  const float* bv = (const float*)d_in[6];
  const float* g  = (const float*)d_in[7];

  unsigned short* ws = (unsigned short*)d_ws;
  unsigned short* qb = ws;                 // 4*4096*16 bf16 = 512 KB
  unsigned short* kb = ws + 262144;        // 512 KB
  unsigned short* vb = ws + 524288;        // 4*64*4096 bf16 = 2 MB
  float* Opart = (float*)((char*)d_ws + (size_t)4 * 1024 * 1024);   // 64 MB
  float* lpart = (float*)((char*)d_ws + (size_t)68 * 1024 * 1024);  // 1 MB
  float* ob = (float*)d_out;

  hipLaunchKernelGGL(qkv_mfma, dim3(6, 64, 4), dim3(256), 0, stream,
                     x, Wq, bq, Wk, bk, Wv, bv, qb, kb, vb);
  hipLaunchKernelGGL(flash_attn, dim3(NSPLIT, 16, 4), dim3(256), 0, stream,
                     qb, kb, vb, Opart, lpart);
  hipLaunchKernelGGL(finalize, dim3(64, 4), dim3(1024), 0, stream,
                     Opart, lpart, x, g, ob);
}

// Round 9
// 112.951 us; speedup vs baseline: 1.0763x; 1.0763x over previous
//
#include <hip/hip_runtime.h>

typedef short short8  __attribute__((ext_vector_type(8)));
typedef short short4v __attribute__((ext_vector_type(4)));
typedef float f32x4   __attribute__((ext_vector_type(4)));

#define NSPLIT 8

static __device__ __forceinline__ unsigned short f2bf(float f) {
  unsigned int u = __builtin_bit_cast(unsigned int, f);
  u += 0x7fffu + ((u >> 16) & 1u);   // RNE
  return (unsigned short)(u >> 16);
}
static __device__ __forceinline__ float bf2f(unsigned short u) {
  unsigned int v = ((unsigned int)u) << 16;
  return __builtin_bit_cast(float, v);
}
// pack two f32 -> two bf16 (RTZ) in ONE v_perm_b32: D = [hi.b3 hi.b2 lo.b3 lo.b2]
static __device__ __forceinline__ unsigned int pack2bf_rtz(float lo, float hi) {
  return __builtin_amdgcn_perm(__builtin_bit_cast(unsigned int, hi),
                               __builtin_bit_cast(unsigned int, lo), 0x07060302u);
}

// ---------------------------------------------------------------------------
// Kernel 1: QKV projection GEMM, rt-split (grid 6x64x4, 24 waves/CU).
// rt0=Q (PRE-SCALED by log2(e) so flash can use exp2), rt1=K, rt2..5=V rows.
// Q,K -> bf16 [b][n][16]; V -> bf16 [b][c][n].
// ---------------------------------------------------------------------------
__global__ __launch_bounds__(256) void qkv_mfma(
    const float* __restrict__ x,
    const float* __restrict__ Wq, const float* __restrict__ bq,
    const float* __restrict__ Wk, const float* __restrict__ bk,
    const float* __restrict__ Wv, const float* __restrict__ bv,
    unsigned short* __restrict__ qb, unsigned short* __restrict__ kb,
    unsigned short* __restrict__ vb)
{
  const int rt   = blockIdx.x;         // 0..5
  const int nt   = blockIdx.y;         // 0..63
  const int b    = blockIdx.z;         // 0..3
  const int lane = threadIdx.x & 63;
  const int wave = threadIdx.x >> 6;
  const int l15  = lane & 15;
  const int quad = lane >> 4;
  const int n    = nt * 64 + wave * 16 + l15;

  const float* wbase; const float* bias; int row0;
  if (rt == 0)      { wbase = Wq; bias = bq; row0 = 0; }
  else if (rt == 1) { wbase = Wk; bias = bk; row0 = 0; }
  else              { wbase = Wv; bias = bv; row0 = (rt - 2) * 16; }

  short8 bfrag[2];
#pragma unroll
  for (int ks = 0; ks < 2; ++ks)
#pragma unroll
    for (int jj = 0; jj < 8; ++jj) {
      const int c = ks * 32 + quad * 8 + jj;
      bfrag[ks][jj] = (short)f2bf(x[((size_t)(b * 64 + c)) * 4096 + n]);
    }

  short8 afrag[2];
#pragma unroll
  for (int ks = 0; ks < 2; ++ks) {
    f32x4 w0 = *(const f32x4*)(wbase + (row0 + l15) * 64 + ks * 32 + quad * 8);
    f32x4 w1 = *(const f32x4*)(wbase + (row0 + l15) * 64 + ks * 32 + quad * 8 + 4);
#pragma unroll
    for (int jj = 0; jj < 4; ++jj) {
      afrag[ks][jj]     = (short)f2bf(w0[jj]);
      afrag[ks][jj + 4] = (short)f2bf(w1[jj]);
    }
  }

  f32x4 acc;
#pragma unroll
  for (int r = 0; r < 4; ++r)
    acc[r] = bias[row0 + quad * 4 + r];
  acc = __builtin_amdgcn_mfma_f32_16x16x32_bf16(afrag[0], bfrag[0], acc, 0, 0, 0);
  acc = __builtin_amdgcn_mfma_f32_16x16x32_bf16(afrag[1], bfrag[1], acc, 0, 0, 0);

  if (rt <= 1) {
    if (rt == 0) {
#pragma unroll
      for (int r = 0; r < 4; ++r) acc[r] *= 1.44269504088896340736f;  // log2(e)
    }
    short4v sv;
#pragma unroll
    for (int r = 0; r < 4; ++r) sv[r] = (short)f2bf(acc[r]);
    unsigned short* dst = (rt == 0 ? qb : kb);
    *(short4v*)(dst + (((size_t)b * 4096 + n) * 16) + quad * 4) = sv;
  } else {
#pragma unroll
    for (int r = 0; r < 4; ++r) {
      const int c = row0 + quad * 4 + r;
      vb[((size_t)(b * 64 + c)) * 4096 + n] = f2bf(acc[r]);
    }
  }
}

// ---------------------------------------------------------------------------
// Kernel 2: flash partials, 64 queries per wave, software-pipelined j-loop
// (vf loads hidden under S/exp phase, next-iter kf under PV).  Barrier-free;
// P via per-wave swizzled LDS; exp2 (Q pre-scaled).  NSPLIT=8 -> grid
// 8x16x4 = 512 blocks (2/CU), 8 j-iters each.  O-partials stored BF16
// (RNE), halving partial-stream bytes; exactness: partials are additive
// (no-max softmax), bf16 rel-err ~0.4% well inside the 0.099 budget.
// ---------------------------------------------------------------------------
__global__ __launch_bounds__(256) void flash_attn(
    const unsigned short* __restrict__ qb, const unsigned short* __restrict__ kb,
    const unsigned short* __restrict__ vb,
    unsigned short* __restrict__ Opart, float* __restrict__ lpart)
{
  __shared__ unsigned short p_lds[4][64 * 64];   // per-wave [q64][j64], swizzled

  const int s    = blockIdx.x;          // 0..NSPLIT-1
  const int qw4  = blockIdx.y;          // 0..15
  const int b    = blockIdx.z;          // 0..3
  const int t    = threadIdx.x;
  const int wave = t >> 6;
  const int lane = t & 63;
  const int l15  = lane & 15;
  const int quad = lane >> 4;
  const int sw   = l15 & 7;
  const int qw   = qw4 * 4 + wave;      // 64-query wave index 0..63

  short8 qfrag[4];
#pragma unroll
  for (int qt = 0; qt < 4; ++qt) {
    qfrag[qt] = (short8)0;
    if (quad < 2) {
      const int iq = qw * 64 + qt * 16 + l15;
      qfrag[qt] = *(const short8*)(qb + (((size_t)b * 4096 + iq) * 16 + quad * 8));
    }
  }

  const unsigned short* vbb = vb + (size_t)b * 64 * 4096;
  const unsigned short* kbb = kb + (size_t)b * 4096 * 16;
  f32x4 acc[4][4];
#pragma unroll
  for (int qt = 0; qt < 4; ++qt)
#pragma unroll
    for (int ct = 0; ct < 4; ++ct) acc[qt][ct] = (f32x4)0.f;
  float lp[4] = {0.f, 0.f, 0.f, 0.f};
  unsigned short* pw = &p_lds[wave][0];

  const int jbeg = s * (4096 / NSPLIT);
  const int jend = jbeg + 4096 / NSPLIT;

  short8 kf[4];
#pragma unroll
  for (int sub = 0; sub < 4; ++sub) {
    kf[sub] = (short8)0;
    if (quad < 2)
      kf[sub] = *(const short8*)(kbb + (size_t)(jbeg + sub * 16 + l15) * 16 + quad * 8);
  }

#pragma unroll 1
  for (int j0 = jbeg; j0 < jend; j0 += 64) {
    short8 vf[2][4];
#pragma unroll
    for (int kc = 0; kc < 2; ++kc) {
      const int vcol = j0 + kc * 32 + quad * 8;
#pragma unroll
      for (int ct = 0; ct < 4; ++ct)
        vf[kc][ct] = *(const short8*)(vbb + (size_t)(ct * 16 + l15) * 4096 + vcol);
    }

#pragma unroll
    for (int qt = 0; qt < 4; ++qt) {
#pragma unroll
      for (int sub = 0; sub < 4; ++sub) {
        f32x4 sc = __builtin_amdgcn_mfma_f32_16x16x32_bf16(kf[sub], qfrag[qt], (f32x4)0.f, 0, 0, 0);
        float p0 = exp2f(sc[0]);
        float p1 = exp2f(sc[1]);
        float p2 = exp2f(sc[2]);
        float p3 = exp2f(sc[3]);
        lp[qt] += (p0 + p1) + (p2 + p3);
        const int ch = (sub * 2 + (quad >> 1)) ^ sw;
        unsigned int* dst = (unsigned int*)(pw + (qt * 16 + l15) * 64 + ch * 8 + (quad & 1) * 4);
        dst[0] = pack2bf_rtz(p0, p1);
        dst[1] = pack2bf_rtz(p2, p3);
      }
    }

    short8 kfn[4];
    const int jn = j0 + 64;
    const bool more = (jn < jend);
#pragma unroll
    for (int sub = 0; sub < 4; ++sub) {
      kfn[sub] = (short8)0;
      if (more && quad < 2)
        kfn[sub] = *(const short8*)(kbb + (size_t)(jn + sub * 16 + l15) * 16 + quad * 8);
    }

#pragma unroll
    for (int kc = 0; kc < 2; ++kc) {
#pragma unroll
      for (int qt = 0; qt < 4; ++qt) {
        short8 pf = *(const short8*)(pw + (qt * 16 + l15) * 64 + ((kc * 4 + quad) ^ sw) * 8);
#pragma unroll
        for (int ct = 0; ct < 4; ++ct)
          acc[qt][ct] = __builtin_amdgcn_mfma_f32_16x16x32_bf16(vf[kc][ct], pf, acc[qt][ct], 0, 0, 0);
      }
    }

#pragma unroll
    for (int sub = 0; sub < 4; ++sub) kf[sub] = kfn[sub];
  }

#pragma unroll
  for (int qt = 0; qt < 4; ++qt) {
    lp[qt] += __shfl_xor(lp[qt], 16);
    lp[qt] += __shfl_xor(lp[qt], 32);
  }

  const int pslot = (b * 64 + qw) * NSPLIT + s;
  unsigned short* Op = Opart + (size_t)pslot * 4096;   // [q64][c64] bf16
#pragma unroll
  for (int qt = 0; qt < 4; ++qt)
#pragma unroll
    for (int ct = 0; ct < 4; ++ct) {
      short4v sv;
#pragma unroll
      for (int r = 0; r < 4; ++r) sv[r] = (short)f2bf(acc[qt][ct][r]);  // RNE
      *(short4v*)(Op + (qt * 16 + l15) * 64 + ct * 16 + quad * 4) = sv;
    }
  if (lane < 16) {
#pragma unroll
    for (int qt = 0; qt < 4; ++qt)
      lpart[(size_t)pslot * 64 + qt * 16 + lane] = lp[qt];
  }
}

// ---------------------------------------------------------------------------
// Kernel 3: combine NSPLIT bf16 partials, normalize, gamma*O + x.
// Grid 64x4, 1024 threads.  Per-thread element block: q = t>>4,
// c = (t&15)*4 + r  ->  Opart offset 4*t shorts (lane-consecutive 8 B).
// ---------------------------------------------------------------------------
__global__ __launch_bounds__(1024) void finalize(
    const unsigned short* __restrict__ Opart, const float* __restrict__ lpart,
    const float* __restrict__ x, const float* __restrict__ gptr,
    float* __restrict__ out)
{
  __shared__ float osum[64 * 65];
  __shared__ float linv[64];

  const int qw = blockIdx.x;            // 0..63 (64-query group)
  const int b  = blockIdx.y;            // 0..3
  const int t  = threadIdx.x;           // 0..1023
  const int base = (b * 64 + qw) * NSPLIT;

  if (t < 64) {
    float sum = 0.f;
#pragma unroll
    for (int s = 0; s < NSPLIT; ++s) sum += lpart[(size_t)(base + s) * 64 + t];
    linv[t] = 1.f / sum;
  }

  f32x4 o = (f32x4)0.f;
  const unsigned short* Op = Opart + (size_t)base * 4096;
#pragma unroll
  for (int s = 0; s < NSPLIT; ++s) {
    short4v v = *(const short4v*)(Op + (size_t)s * 4096 + 4 * t);
#pragma unroll
    for (int r = 0; r < 4; ++r)
      o[r] += bf2f((unsigned short)v[r]);
  }

  const int q  = t >> 4;
  const int c0 = (t & 15) * 4;
#pragma unroll
  for (int r = 0; r < 4; ++r)
    osum[(c0 + r) * 65 + q] = o[r];
  __syncthreads();

  const float g  = gptr[0];
  const int   qq = t & 63;
  const float li = linv[qq];
#pragma unroll
  for (int i = 0; i < 4; ++i) {
    const int c = (t >> 6) + 16 * i;
    const size_t off = ((size_t)(b * 64 + c)) * 4096 + qw * 64 + qq;
    out[off] = g * (osum[c * 65 + qq] * li) + x[off];
  }
}

// ---------------------------------------------------------------------------
extern "C" void kernel_launch(void* const* d_in, const int* in_sizes, int n_in,
                              void* d_out, int out_size, void* d_ws, size_t ws_size,
                              hipStream_t stream)
{
  const float* x  = (const float*)d_in[0];
  const float* Wq = (const float*)d_in[1];
  const float* bq = (const float*)d_in[2];
  const float* Wk = (const float*)d_in[3];
  const float* bk = (const float*)d_in[4];
  const float* Wv = (const float*)d_in[5];
  const float* bv = (const float*)d_in[6];
  const float* g  = (const float*)d_in[7];

  unsigned short* ws = (unsigned short*)d_ws;
  unsigned short* qb = ws;                 // 4*4096*16 bf16 = 512 KB
  unsigned short* kb = ws + 262144;        // 512 KB
  unsigned short* vb = ws + 524288;        // 4*64*4096 bf16 = 2 MB
  unsigned short* Opart = (unsigned short*)((char*)d_ws + (size_t)4 * 1024 * 1024); // 2048*4096 bf16 = 16 MB
  float* lpart = (float*)((char*)d_ws + (size_t)24 * 1024 * 1024);  // 512 KB
  float* ob = (float*)d_out;

  hipLaunchKernelGGL(qkv_mfma, dim3(6, 64, 4), dim3(256), 0, stream,
                     x, Wq, bq, Wk, bk, Wv, bv, qb, kb, vb);
  hipLaunchKernelGGL(flash_attn, dim3(NSPLIT, 16, 4), dim3(256), 0, stream,
                     qb, kb, vb, Opart, lpart);
  hipLaunchKernelGGL(finalize, dim3(64, 4), dim3(1024), 0, stream,
                     Opart, lpart, x, g, ob);
}